// Round 3
// 124.630 us; speedup vs baseline: 1.0208x; 1.0208x over previous
//
#include <hip/hip_runtime.h>

// Problem constants (from reference)
constexpr int B_  = 2;
constexpr int T_  = 1024;
constexpr int NQ  = 32;
constexpr int NKV = 8;
constexpr int D_  = 128;

constexpr int BM = 64;            // query rows per workgroup (4 waves x 16)
constexpr int BN = 64;            // keys per KV iteration
constexpr int NTILE = T_ / BM;    // 16 q-tiles = 16 kv-blocks of 64
constexpr float MASK_NEG = -3.0e38f;

typedef _Float16 f16;
typedef __fp16 fp16_2 __attribute__((ext_vector_type(2)));
typedef f16 f16x4 __attribute__((ext_vector_type(4)));
typedef f16 f16x8 __attribute__((ext_vector_type(8)));
typedef float floatx4 __attribute__((ext_vector_type(4)));
typedef unsigned int uintx4 __attribute__((ext_vector_type(4)));

// Static device scratch (NOT d_ws: prep fully rewrites both arrays every call).
//   K16 [b][kv][s][ch^ (s&7)]  (16 chunks of 8 f16 per 128-d row)
//   Vt16 [b][kv][blk][d][ch ^ (d&7)] (transposed; 8 chunks of 8 f16 per 64-s row)
__device__ __align__(16) f16 g_K16 [(size_t)B_ * NKV * T_ * D_];   // 4 MB
__device__ __align__(16) f16 g_Vt16[(size_t)B_ * NKV * T_ * D_];   // 4 MB

__device__ __forceinline__ void dma16(const f16* g, const f16* l) {
    // async global->LDS, 16 B/lane, lands at lds_base + lane*16
    __builtin_amdgcn_global_load_lds(
        (const __attribute__((address_space(1))) void*)g,
        (__attribute__((address_space(3))) void*)l, 16, 0, 0);
}

// ---- cross-lane swap helpers (shfl_xor based: unambiguous semantics) ----
// after: a' = {a_lo, b_lo}, b' = {a_hi, b_hi}   (32-lane halves)
__device__ __forceinline__ void swap32(unsigned &a, unsigned &b) {
    unsigned ax = (unsigned)__shfl_xor((int)a, 32);
    unsigned bx = (unsigned)__shfl_xor((int)b, 32);
    const bool hi = (threadIdx.x & 32) != 0;
    unsigned na = hi ? bx : a;     // lanes 0-31: a_lo ; lanes 32-63: b_lo
    unsigned nb = hi ? b  : ax;    // lanes 0-31: a_hi ; lanes 32-63: b_hi
    a = na; b = nb;
}

// after: a' = {a0, b0, a2, b2}, b' = {a1, b1, a3, b3}   (16-lane rows)
__device__ __forceinline__ void swap16(unsigned &a, unsigned &b) {
    unsigned ax = (unsigned)__shfl_xor((int)a, 16);
    unsigned bx = (unsigned)__shfl_xor((int)b, 16);
    const bool odd = (threadIdx.x & 16) != 0;
    unsigned na = odd ? bx : a;    // even rows keep a ; odd rows take b's even row
    unsigned nb = odd ? b  : ax;   // odd rows keep b  ; even rows take a's odd row
    a = na; b = nb;
}

// pack two f32 -> one dword of 2 f16 (RTZ)
__device__ __forceinline__ unsigned pk2(float a, float b) {
    union { fp16_2 h; unsigned u; } c;
    c.h = __builtin_amdgcn_cvt_pkrtz(a, b);
    return c.u;
}

// ---------------------------------------------------------------------------
// Prep: fp32 K/V -> fp16, relayout + XOR-swizzle (unchanged, proven)
__global__ __launch_bounds__(256)
void prep_kernel(const float* __restrict__ K, const float* __restrict__ V) {
    __shared__ f16 lv[64][136];
    const int sblk = blockIdx.x;   // 0..15
    const int kv   = blockIdx.y;   // 0..7
    const int b    = blockIdx.z;   // 0..1
    const int tid  = threadIdx.x;
    const int s0   = sblk * 64;
    const size_t inbase = ((size_t)b * T_) * NKV * D_ + (size_t)kv * D_;

    f16* kout = g_K16 + ((size_t)(b * NKV + kv) * T_ + s0) * D_;
#pragma unroll
    for (int p = 0; p < 4; ++p) {
        const int u = tid + 256 * p;          // 1024 chunk units (16 B each)
        const int s = u >> 4, ch = u & 15;
        const float* src = K + inbase + (size_t)(s0 + s) * NKV * D_ + ch * 8;
        float4 f0 = *(const float4*)src;
        float4 f1 = *(const float4*)(src + 4);
        f16x8 hh;
        hh[0] = (f16)f0.x; hh[1] = (f16)f0.y; hh[2] = (f16)f0.z; hh[3] = (f16)f0.w;
        hh[4] = (f16)f1.x; hh[5] = (f16)f1.y; hh[6] = (f16)f1.z; hh[7] = (f16)f1.w;
        *(f16x8*)(kout + s * D_ + ((ch ^ (s & 7)) * 8)) = hh;
    }
#pragma unroll
    for (int p = 0; p < 8; ++p) {
        const int u = tid + 256 * p;
        const int s = u >> 5, d4 = u & 31;
        float4 f = *(const float4*)(V + inbase + (size_t)(s0 + s) * NKV * D_ + d4 * 4);
        f16x4 hh; hh[0] = (f16)f.x; hh[1] = (f16)f.y; hh[2] = (f16)f.z; hh[3] = (f16)f.w;
        *(f16x4*)&lv[s][d4 * 4] = hh;
    }
    __syncthreads();
    f16* vout = g_Vt16 + (size_t)((b * NKV + kv) * 16 + sblk) * 8192;
#pragma unroll
    for (int p = 0; p < 4; ++p) {
        const int u = tid + 256 * p;          // 1024 8-f16 units
        const int d = u >> 3, cu = u & 7;
        f16x8 hh;
#pragma unroll
        for (int j = 0; j < 8; ++j) hh[j] = lv[cu * 8 + j][d];
        *(f16x8*)(vout + d * 64 + ((cu ^ (d & 7)) * 8)) = hh;
    }
}

// ---------------------------------------------------------------------------
// Body macro: one KV block. Swapped QK^T (A=K, B=Q) puts key on rows
// (quad*4+r) and q on ln, so:
//  - softmax row-reduce is 2 shfl_xor steps (was 16)
//  - P transposes to the PV A-fragment IN REGISTERS via cvt_pkrtz + swaps
//    (was 16 ds_write + lgkmcnt(0) + 2 ds_read)
//  - masking is two integer compares vs per-lane [fs_l, qrow_l] bounds
#define FA_BODY(RK, RV, WK, WV, blkv)                                          \
    {                                                                          \
        const int s0 = (blkv) * BN;                                            \
        __syncthreads();                                                       \
        if ((blkv) + 1 < nblk) {                                               \
            const f16* kt = kbase + (size_t)((blkv) + 1) * 8192 + glane;       \
            const f16* vt = vbase + (size_t)((blkv) + 1) * 8192 + glane;       \
            _Pragma("unroll")                                                  \
            for (int i = 0; i < 4; ++i) {                                      \
                dma16(kt + i * 512, WK + wbase + i * 512);                     \
                dma16(vt + i * 512, WV + wbase + i * 512);                     \
            }                                                                  \
        }                                                                      \
        floatx4 sc[4];                                                         \
        _Pragma("unroll")                                                      \
        for (int nt = 0; nt < 4; ++nt) {                                       \
            floatx4 acc = floatx4{0.f, 0.f, 0.f, 0.f};                         \
            _Pragma("unroll")                                                  \
            for (int c = 0; c < 4; ++c) {                                      \
                f16x8 kf = *(const f16x8*)(RK + (nt * 16 + ln) * 128 + kpc[c]);\
                acc = __builtin_amdgcn_mfma_f32_16x16x32_f16(kf, qfrag[c], acc, 0, 0, 0); \
            }                                                                  \
            sc[nt] = acc;                                                      \
        }                                                                      \
        _Pragma("unroll")                                                      \
        for (int nt = 0; nt < 4; ++nt) {                                       \
            _Pragma("unroll")                                                  \
            for (int r = 0; r < 4; ++r) {                                      \
                const int s = s0 + nt * 16 + quad * 4 + r;                     \
                const bool ok = (s <= qrow_l) && (s >= fs_l);                  \
                sc[nt][r] = ok ? sc[nt][r] : MASK_NEG;                         \
            }                                                                  \
        }                                                                      \
        float mx = fmaxf(                                                      \
            fmaxf(fmaxf(fmaxf(sc[0][0], sc[0][1]), fmaxf(sc[0][2], sc[0][3])), \
                  fmaxf(fmaxf(sc[1][0], sc[1][1]), fmaxf(sc[1][2], sc[1][3]))),\
            fmaxf(fmaxf(fmaxf(sc[2][0], sc[2][1]), fmaxf(sc[2][2], sc[2][3])), \
                  fmaxf(fmaxf(sc[3][0], sc[3][1]), fmaxf(sc[3][2], sc[3][3]))));\
        mx = fmaxf(mx, __shfl_xor(mx, 16));                                    \
        mx = fmaxf(mx, __shfl_xor(mx, 32));                                    \
        const float mnew = fmaxf(m_i, mx);                                     \
        const float av = __expf(m_i - mnew);                                   \
        m_i = mnew;                                                            \
        _Pragma("unroll")                                                      \
        for (int nt = 0; nt < 4; ++nt) {                                       \
            sc[nt][0] = __expf(sc[nt][0] - mnew);                              \
            sc[nt][1] = __expf(sc[nt][1] - mnew);                              \
            sc[nt][2] = __expf(sc[nt][2] - mnew);                              \
            sc[nt][3] = __expf(sc[nt][3] - mnew);                              \
        }                                                                      \
        const int avi = __float_as_int(av);                                    \
        floatx4 avr;                                                           \
        _Pragma("unroll")                                                      \
        for (int r = 0; r < 4; ++r)                                            \
            avr[r] = __int_as_float(__builtin_amdgcn_ds_bpermute(bpbase + 4 * r, avi)); \
        _Pragma("unroll")                                                      \
        for (int dt = 0; dt < 9; ++dt) o_acc[dt] *= avr;                       \
        unsigned Da[4], Db[4];                                                 \
        _Pragma("unroll")                                                      \
        for (int nt = 0; nt < 4; ++nt) {                                       \
            Da[nt] = pk2(sc[nt][0], sc[nt][1]);                                \
            Db[nt] = pk2(sc[nt][2], sc[nt][3]);                                \
        }                                                                      \
        swap32(Da[0], Da[1]); swap32(Db[0], Db[1]);                            \
        swap16(Da[0], Da[1]); swap16(Db[0], Db[1]);                            \
        swap32(Da[2], Da[3]); swap32(Db[2], Db[3]);                            \
        swap16(Da[2], Da[3]); swap16(Db[2], Db[3]);                            \
        union { uintx4 u; f16x8 h; } c0_, c1_;                                 \
        c0_.u = uintx4{Da[0], Db[0], Da[1], Db[1]};                            \
        c1_.u = uintx4{Da[2], Db[2], Da[3], Db[3]};                            \
        const f16x8 af0 = c0_.h;                                               \
        const f16x8 af1 = c1_.h;                                               \
        _Pragma("unroll")                                                      \
        for (int dt = 0; dt < 8; ++dt) {                                       \
            const f16* vr = RV + (dt * 16 + ln) * 64;                          \
            f16x8 b0 = *(const f16x8*)(vr + pc0);                              \
            f16x8 b1 = *(const f16x8*)(vr + pc1);                              \
            o_acc[dt] = __builtin_amdgcn_mfma_f32_16x16x32_f16(af0, b0, o_acc[dt], 0, 0, 0); \
            o_acc[dt] = __builtin_amdgcn_mfma_f32_16x16x32_f16(af1, b1, o_acc[dt], 0, 0, 0); \
        }                                                                      \
        o_acc[8] = __builtin_amdgcn_mfma_f32_16x16x32_f16(af0, vones, o_acc[8], 0, 0, 0); \
        o_acc[8] = __builtin_amdgcn_mfma_f32_16x16x32_f16(af1, vones, o_acc[8], 0, 0, 0); \
    }

__global__ __launch_bounds__(256, 2)
void fa_kernel(const float* __restrict__ Qg, const int* __restrict__ seg,
               float* __restrict__ Og) {
    __shared__ __align__(16) f16 kb0[64 * 128];   // 16 KB each, unpadded
    __shared__ __align__(16) f16 kb1[64 * 128];
    __shared__ __align__(16) f16 vb0[128 * 64];
    __shared__ __align__(16) f16 vb1[128 * 64];
    __shared__ int lds_seg[T_];                   // 4096 B  (total 68 KB)

    const int pair = blockIdx.x;        // 0..7
    const int h    = blockIdx.y;        // 0..31
    const int b    = blockIdx.z;        // 0..1
    const int kv   = h >> 2;

    const int tid  = threadIdx.x;
    const int wave = tid >> 6;
    const int lane = tid & 63;
    const int quad = lane >> 4;
    const int ln   = lane & 15;
    const int sw   = ln & 7;

    // deswizzle constants (per-lane loop invariants), in f16 units
    int kpc[4];
#pragma unroll
    for (int c = 0; c < 4; ++c) kpc[c] = ((4 * c + quad) ^ sw) * 8;
    const int pc0 = (quad ^ sw) * 8;
    const int pc1 = ((quad + 4) ^ sw) * 8;
    const int bpbase = quad << 4;                 // ds_bpermute addr base

    // DMA offsets: wave w stages rows [16w,16w+16) of each tile
    const int glane = wave * 2048 + lane * 8;   // per-lane global (f16 units)
    const int wbase = wave * 2048;              // uniform LDS base (f16 units)

    const f16* kbase = g_K16 + (size_t)(b * NKV + kv) * T_ * D_;
    const f16* vbase = g_Vt16 + (size_t)(b * NKV + kv) * T_ * D_;

    *(int4*)&lds_seg[tid * 4] = *(const int4*)(seg + b * T_ + tid * 4);

    f16x8 vones;
#pragma unroll
    for (int j = 0; j < 8; ++j) vones[j] = (f16)1.0f;

    for (int sub = 0; sub < 2; ++sub) {
        const int tile = sub ? pair : (NTILE - 1 - pair);  // heavy tile first
        const int t0 = tile * BM;

        // ---- Q fragments (B-layout for swapped QK: n = ln, k = quad*8+j)
        const int qrow = t0 + wave * 16 + ln;
        const float* qptr = Qg + (((size_t)b * T_ + qrow) * NQ + h) * D_;
        f16x8 qfrag[4];
#pragma unroll
        for (int c = 0; c < 4; ++c) {
            const float* p = qptr + c * 32 + quad * 8;
            float4 f0 = *(const float4*)(p);
            float4 f1 = *(const float4*)(p + 4);
            f16x8 v;
            v[0] = (f16)f0.x; v[1] = (f16)f0.y; v[2] = (f16)f0.z; v[3] = (f16)f0.w;
            v[4] = (f16)f1.x; v[5] = (f16)f1.y; v[6] = (f16)f1.z; v[7] = (f16)f1.w;
            qfrag[c] = v;
        }

        __syncthreads();   // lds_seg visible (first sub) / prev sub's reads done

        int trow[4];
#pragma unroll
        for (int r = 0; r < 4; ++r) trow[r] = t0 + wave * 16 + quad * 4 + r;

        // per-lane mask bounds: seg ids sorted, so (seg[s]==seg[q] && s<=q)
        // <=> fs_l <= s <= qrow_l, fs_l = segment start of row qrow_l
        const int qrow_l = qrow;
        const int segq_l = lds_seg[qrow_l];
        int lo = 0, hi = qrow_l;
        while (lo < hi) {
            const int mid = (lo + hi) >> 1;
            if (lds_seg[mid] < segq_l) lo = mid + 1; else hi = mid;
        }
        const int fs_l = lo;

        const int seg_lo = lds_seg[t0];
        // first active KV block (sorted ids): ballot over dead 16-chunks
        unsigned long long bal = __ballot(lds_seg[lane * 16 + 15] < seg_lo);
        const int blk_start = __popcll(bal) >> 2;
        const int nblk = tile + 1;      // causal limit

        float  m_i = -1.0e30f;
        floatx4 o_acc[9];               // [8] = running row-sum (ones column)
#pragma unroll
        for (int dt = 0; dt < 9; ++dt) o_acc[dt] = floatx4{0.f, 0.f, 0.f, 0.f};

        // ---- prologue: DMA first block into buf 0 (drained by first body barrier)
        {
            const f16* kt = kbase + (size_t)blk_start * 8192 + glane;
            const f16* vt = vbase + (size_t)blk_start * 8192 + glane;
#pragma unroll
            for (int i = 0; i < 4; ++i) {
                dma16(kt + i * 512, kb0 + wbase + i * 512);
                dma16(vt + i * 512, vb0 + wbase + i * 512);
            }
        }

        int blk = blk_start;
        while (true) {
            FA_BODY(kb0, vb0, kb1, vb1, blk)
            if (++blk >= nblk) break;
            FA_BODY(kb1, vb1, kb0, vb0, blk)
            if (++blk >= nblk) break;
        }

        // ---- epilogue: normalize + store (fp32, C-layout scatter)
#pragma unroll
        for (int r = 0; r < 4; ++r) {
            const float inv = 1.0f / o_acc[8][r];
            float* optr = Og + (((size_t)b * T_ + trow[r]) * NQ + h) * D_ + ln;
#pragma unroll
            for (int dt = 0; dt < 8; ++dt)
                optr[dt * 16] = o_acc[dt][r] * inv;
        }
    }
}

extern "C" void kernel_launch(void* const* d_in, const int* in_sizes, int n_in,
                              void* d_out, int out_size, void* d_ws, size_t ws_size,
                              hipStream_t stream) {
    const float* Q   = (const float*)d_in[0];
    const float* K   = (const float*)d_in[1];
    const float* V   = (const float*)d_in[2];
    const int*   seg = (const int*)d_in[3];
    float* out = (float*)d_out;

    dim3 pgrid(NTILE, NKV, B_);
    prep_kernel<<<pgrid, 256, 0, stream>>>(K, V);

    dim3 grid(NTILE / 2, NQ, B_);
    fa_kernel<<<grid, 256, 0, stream>>>(Q, seg, out);
}

// Round 4
// 121.127 us; speedup vs baseline: 1.0503x; 1.0289x over previous
//
#include <hip/hip_runtime.h>

// Problem constants (from reference)
constexpr int B_  = 2;
constexpr int T_  = 1024;
constexpr int NQ  = 32;
constexpr int NKV = 8;
constexpr int D_  = 128;

constexpr int BM = 128;           // query rows per workgroup (4 waves x 32)
constexpr int BN = 64;            // keys per KV iteration
constexpr int NTILE = T_ / BM;    // 8 q-tiles per (b,h)
constexpr float MASK_NEG = -3.0e38f;

typedef _Float16 f16;
typedef __fp16 fp16_2 __attribute__((ext_vector_type(2)));
typedef f16 f16x4 __attribute__((ext_vector_type(4)));
typedef f16 f16x8 __attribute__((ext_vector_type(8)));
typedef float floatx4 __attribute__((ext_vector_type(4)));

// Static device scratch (NOT d_ws: prep fully rewrites both arrays every call).
//   K16 [b][kv][s][ch^ (s&7)]  (16 chunks of 8 f16 per 128-d row)
//   Vt16 [b][kv][blk][d][ch ^ (d&7)] (transposed; 8 chunks of 8 f16 per 64-s row)
__device__ __align__(16) f16 g_K16 [(size_t)B_ * NKV * T_ * D_];   // 4 MB
__device__ __align__(16) f16 g_Vt16[(size_t)B_ * NKV * T_ * D_];   // 4 MB

__device__ __forceinline__ void dma16(const f16* g, const f16* l) {
    // async global->LDS, 16 B/lane, lands at lds_base + lane*16
    __builtin_amdgcn_global_load_lds(
        (const __attribute__((address_space(1))) void*)g,
        (__attribute__((address_space(3))) void*)l, 16, 0, 0);
}

// pack two f32 -> one dword of 2 f16 (RTZ)
__device__ __forceinline__ unsigned pk2(float a, float b) {
    union { fp16_2 h; unsigned u; } c;
    c.h = __builtin_amdgcn_cvt_pkrtz(a, b);
    return c.u;
}

// ---------------------------------------------------------------------------
// Prep: fp32 K/V -> fp16, relayout + XOR-swizzle (unchanged, proven)
__global__ __launch_bounds__(256)
void prep_kernel(const float* __restrict__ K, const float* __restrict__ V) {
    __shared__ f16 lv[64][136];
    const int sblk = blockIdx.x;   // 0..15
    const int kv   = blockIdx.y;   // 0..7
    const int b    = blockIdx.z;   // 0..1
    const int tid  = threadIdx.x;
    const int s0   = sblk * 64;
    const size_t inbase = ((size_t)b * T_) * NKV * D_ + (size_t)kv * D_;

    f16* kout = g_K16 + ((size_t)(b * NKV + kv) * T_ + s0) * D_;
#pragma unroll
    for (int p = 0; p < 4; ++p) {
        const int u = tid + 256 * p;          // 1024 chunk units (16 B each)
        const int s = u >> 4, ch = u & 15;
        const float* src = K + inbase + (size_t)(s0 + s) * NKV * D_ + ch * 8;
        float4 f0 = *(const float4*)src;
        float4 f1 = *(const float4*)(src + 4);
        f16x8 hh;
        hh[0] = (f16)f0.x; hh[1] = (f16)f0.y; hh[2] = (f16)f0.z; hh[3] = (f16)f0.w;
        hh[4] = (f16)f1.x; hh[5] = (f16)f1.y; hh[6] = (f16)f1.z; hh[7] = (f16)f1.w;
        *(f16x8*)(kout + s * D_ + ((ch ^ (s & 7)) * 8)) = hh;
    }
#pragma unroll
    for (int p = 0; p < 8; ++p) {
        const int u = tid + 256 * p;
        const int s = u >> 5, d4 = u & 31;
        float4 f = *(const float4*)(V + inbase + (size_t)(s0 + s) * NKV * D_ + d4 * 4);
        f16x4 hh; hh[0] = (f16)f.x; hh[1] = (f16)f.y; hh[2] = (f16)f.z; hh[3] = (f16)f.w;
        *(f16x4*)&lv[s][d4 * 4] = hh;
    }
    __syncthreads();
    f16* vout = g_Vt16 + (size_t)((b * NKV + kv) * 16 + sblk) * 8192;
#pragma unroll
    for (int p = 0; p < 4; ++p) {
        const int u = tid + 256 * p;          // 1024 8-f16 units
        const int d = u >> 3, cu = u & 7;
        f16x8 hh;
#pragma unroll
        for (int j = 0; j < 8; ++j) hh[j] = lv[cu * 8 + j][d];
        *(f16x8*)(vout + d * 64 + ((cu ^ (d & 7)) * 8)) = hh;
    }
}

// ---------------------------------------------------------------------------
// Body: one KV block of 64. Each wave covers 32 q-rows (2 qn subtiles of 16).
//  - QK^T swapped (A=K, B=Q): K b128 fragments read ONCE, used by both qn.
//  - PV uses mfma_f32_16x16x16f16 with O^T orientation (A=V^T, B=P): the x16
//    B layout (k=quad*4+j, n=ln) IS the QK D layout -> P needs NO cross-lane
//    transpose, just cvt_pkrtz packing. av/l_i are per-lane scalars (q=ln).
#define FA_BODY(RK, RV, WK, WV, blkv)                                          \
    {                                                                          \
        const int s0 = (blkv) * BN;                                            \
        __syncthreads();                                                       \
        if ((blkv) + 1 < nblk) {                                               \
            const f16* kt = kbase + (size_t)((blkv) + 1) * 8192 + glane;       \
            const f16* vt = vbase + (size_t)((blkv) + 1) * 8192 + glane;       \
            _Pragma("unroll")                                                  \
            for (int i = 0; i < 4; ++i) {                                      \
                dma16(kt + i * 512, WK + wbase + i * 512);                     \
                dma16(vt + i * 512, WV + wbase + i * 512);                     \
            }                                                                  \
        }                                                                      \
        floatx4 sc[2][4];                                                      \
        _Pragma("unroll")                                                      \
        for (int nt = 0; nt < 4; ++nt) {                                       \
            f16x8 kf[4];                                                       \
            _Pragma("unroll")                                                  \
            for (int c = 0; c < 4; ++c)                                        \
                kf[c] = *(const f16x8*)(RK + (nt * 16 + ln) * 128 + kpc[c]);   \
            _Pragma("unroll")                                                  \
            for (int qn = 0; qn < 2; ++qn) {                                   \
                floatx4 acc = floatx4{0.f, 0.f, 0.f, 0.f};                     \
                _Pragma("unroll")                                              \
                for (int c = 0; c < 4; ++c)                                    \
                    acc = __builtin_amdgcn_mfma_f32_16x16x32_f16(kf[c], qfrag[qn][c], acc, 0, 0, 0); \
                sc[qn][nt] = acc;                                              \
            }                                                                  \
        }                                                                      \
        f16x4 pf[2][4];                                                        \
        _Pragma("unroll")                                                      \
        for (int qn = 0; qn < 2; ++qn) {                                       \
            _Pragma("unroll")                                                  \
            for (int nt = 0; nt < 4; ++nt) {                                   \
                _Pragma("unroll")                                              \
                for (int r = 0; r < 4; ++r) {                                  \
                    const int s = s0 + nt * 16 + quad * 4 + r;                 \
                    const bool ok = (s <= qrow_l[qn]) && (s >= fs_l[qn]);      \
                    sc[qn][nt][r] = ok ? sc[qn][nt][r] : MASK_NEG;             \
                }                                                              \
            }                                                                  \
            float mx = fmaxf(                                                  \
                fmaxf(fmaxf(fmaxf(sc[qn][0][0], sc[qn][0][1]), fmaxf(sc[qn][0][2], sc[qn][0][3])), \
                      fmaxf(fmaxf(sc[qn][1][0], sc[qn][1][1]), fmaxf(sc[qn][1][2], sc[qn][1][3]))), \
                fmaxf(fmaxf(fmaxf(sc[qn][2][0], sc[qn][2][1]), fmaxf(sc[qn][2][2], sc[qn][2][3])), \
                      fmaxf(fmaxf(sc[qn][3][0], sc[qn][3][1]), fmaxf(sc[qn][3][2], sc[qn][3][3])))); \
            mx = fmaxf(mx, __shfl_xor(mx, 16));                                \
            mx = fmaxf(mx, __shfl_xor(mx, 32));                                \
            const float mnew = fmaxf(m_i[qn], mx);                             \
            const float av = __expf(m_i[qn] - mnew);                           \
            m_i[qn] = mnew;                                                    \
            float ts = 0.f;                                                    \
            _Pragma("unroll")                                                  \
            for (int nt = 0; nt < 4; ++nt) {                                   \
                _Pragma("unroll")                                              \
                for (int r = 0; r < 4; ++r) {                                  \
                    sc[qn][nt][r] = __expf(sc[qn][nt][r] - mnew);              \
                    ts += sc[qn][nt][r];                                       \
                }                                                              \
            }                                                                  \
            ts += __shfl_xor(ts, 16);                                          \
            ts += __shfl_xor(ts, 32);                                          \
            l_i[qn] = l_i[qn] * av + ts;                                       \
            _Pragma("unroll")                                                  \
            for (int dt = 0; dt < 8; ++dt) o_acc[qn][dt] *= av;                \
            _Pragma("unroll")                                                  \
            for (int nt = 0; nt < 4; ++nt) {                                   \
                union { unsigned u[2]; f16x4 h; } pu;                          \
                pu.u[0] = pk2(sc[qn][nt][0], sc[qn][nt][1]);                   \
                pu.u[1] = pk2(sc[qn][nt][2], sc[qn][nt][3]);                   \
                pf[qn][nt] = pu.h;                                             \
            }                                                                  \
        }                                                                      \
        _Pragma("unroll")                                                      \
        for (int dt = 0; dt < 8; ++dt) {                                       \
            const f16* vr = RV + (dt * 16 + ln) * 64;                          \
            _Pragma("unroll")                                                  \
            for (int nt = 0; nt < 4; ++nt) {                                   \
                f16x4 va = *(const f16x4*)(vr + vpc[nt]);                      \
                o_acc[0][dt] = __builtin_amdgcn_mfma_f32_16x16x16f16(va, pf[0][nt], o_acc[0][dt], 0, 0, 0); \
                o_acc[1][dt] = __builtin_amdgcn_mfma_f32_16x16x16f16(va, pf[1][nt], o_acc[1][dt], 0, 0, 0); \
            }                                                                  \
        }                                                                      \
    }

__global__ __launch_bounds__(256, 2)
void fa_kernel(const float* __restrict__ Qg, const int* __restrict__ seg,
               float* __restrict__ Og) {
    __shared__ __align__(16) f16 kb0[64 * 128];   // 16 KB each, unpadded
    __shared__ __align__(16) f16 kb1[64 * 128];
    __shared__ __align__(16) f16 vb0[128 * 64];
    __shared__ __align__(16) f16 vb1[128 * 64];
    __shared__ int lds_seg[T_];                   // 4096 B  (total 68 KB -> 2 blocks/CU)

    // balanced tile map: co-resident blocks (id, id+256) get tiles t and 7-t
    // (18 bodies total), and each XCD (fixed x) cycles through all tiles via h.
    const int xt   = (int)((blockIdx.x + blockIdx.y) & 7);
    const int tile = blockIdx.z ? (7 - xt) : xt;
    const int h    = blockIdx.y;        // 0..31
    const int b    = blockIdx.z;        // 0..1
    const int kv   = h >> 2;

    const int tid  = threadIdx.x;
    const int wave = tid >> 6;
    const int lane = tid & 63;
    const int quad = lane >> 4;
    const int ln   = lane & 15;
    const int sw   = ln & 7;

    // deswizzle constants (per-lane loop invariants), in f16 units
    int kpc[4];
#pragma unroll
    for (int c = 0; c < 4; ++c) kpc[c] = ((4 * c + quad) ^ sw) * 8;
    int vpc[4];
#pragma unroll
    for (int nt = 0; nt < 4; ++nt)
        vpc[nt] = (((2 * nt + (quad >> 1)) ^ sw) * 8) + (quad & 1) * 4;

    // DMA offsets: wave w stages rows [16w,16w+16) of each tile
    const int glane = wave * 2048 + lane * 8;   // per-lane global (f16 units)
    const int wbase = wave * 2048;              // uniform LDS base (f16 units)

    const f16* kbase = g_K16 + (size_t)(b * NKV + kv) * T_ * D_;
    const f16* vbase = g_Vt16 + (size_t)(b * NKV + kv) * T_ * D_;

    *(int4*)&lds_seg[tid * 4] = *(const int4*)(seg + b * T_ + tid * 4);

    const int t0 = tile * BM;

    // ---- Q fragments (B-layout for swapped QK: n = ln, k = c*32+quad*8+j)
    int qrow_l[2];
    f16x8 qfrag[2][4];
#pragma unroll
    for (int qn = 0; qn < 2; ++qn) {
        qrow_l[qn] = t0 + wave * 32 + qn * 16 + ln;
        const float* qptr = Qg + (((size_t)b * T_ + qrow_l[qn]) * NQ + h) * D_;
#pragma unroll
        for (int c = 0; c < 4; ++c) {
            const float* p = qptr + c * 32 + quad * 8;
            float4 f0 = *(const float4*)(p);
            float4 f1 = *(const float4*)(p + 4);
            f16x8 v;
            v[0] = (f16)f0.x; v[1] = (f16)f0.y; v[2] = (f16)f0.z; v[3] = (f16)f0.w;
            v[4] = (f16)f1.x; v[5] = (f16)f1.y; v[6] = (f16)f1.z; v[7] = (f16)f1.w;
            qfrag[qn][c] = v;
        }
    }

    __syncthreads();   // lds_seg visible

    // per-lane mask bounds: seg ids sorted, so (seg[s]==seg[q] && s<=q)
    // <=> fs_l <= s <= qrow_l, fs_l = segment start of row qrow_l
    int fs_l[2];
#pragma unroll
    for (int qn = 0; qn < 2; ++qn) {
        const int segq = lds_seg[qrow_l[qn]];
        int lo = 0, hi = qrow_l[qn];
        while (lo < hi) {
            const int mid = (lo + hi) >> 1;
            if (lds_seg[mid] < segq) lo = mid + 1; else hi = mid;
        }
        fs_l[qn] = lo;
    }

    const int seg_lo = lds_seg[t0];
    // first active KV block (sorted ids): ballot over dead 16-chunks
    unsigned long long bal = __ballot(lds_seg[lane * 16 + 15] < seg_lo);
    const int blk_start = __popcll(bal) >> 2;
    const int nblk = 2 * (tile + 1);    // causal limit (BM=128 -> 2 blocks/tile)

    float  m_i[2] = { -1.0e30f, -1.0e30f };
    float  l_i[2] = { 0.f, 0.f };
    floatx4 o_acc[2][8];
#pragma unroll
    for (int qn = 0; qn < 2; ++qn)
#pragma unroll
        for (int dt = 0; dt < 8; ++dt) o_acc[qn][dt] = floatx4{0.f, 0.f, 0.f, 0.f};

    // ---- prologue: DMA first block into buf 0 (drained by first body barrier)
    {
        const f16* kt = kbase + (size_t)blk_start * 8192 + glane;
        const f16* vt = vbase + (size_t)blk_start * 8192 + glane;
#pragma unroll
        for (int i = 0; i < 4; ++i) {
            dma16(kt + i * 512, kb0 + wbase + i * 512);
            dma16(vt + i * 512, vb0 + wbase + i * 512);
        }
    }

    int blk = blk_start;
    while (true) {
        FA_BODY(kb0, vb0, kb1, vb1, blk)
        if (++blk >= nblk) break;
        FA_BODY(kb1, vb1, kb0, vb0, blk)
        if (++blk >= nblk) break;
    }

    // ---- epilogue: normalize + store (fp32, float4 per dt: d = dt*16+quad*4+r)
#pragma unroll
    for (int qn = 0; qn < 2; ++qn) {
        const float inv = 1.0f / l_i[qn];
        float* optr = Og + (((size_t)b * T_ + qrow_l[qn]) * NQ + h) * D_;
#pragma unroll
        for (int dt = 0; dt < 8; ++dt) {
            floatx4 o = o_acc[qn][dt];
            o[0] *= inv; o[1] *= inv; o[2] *= inv; o[3] *= inv;
            *(floatx4*)(optr + dt * 16 + quad * 4) = o;
        }
    }
}

extern "C" void kernel_launch(void* const* d_in, const int* in_sizes, int n_in,
                              void* d_out, int out_size, void* d_ws, size_t ws_size,
                              hipStream_t stream) {
    const float* Q   = (const float*)d_in[0];
    const float* K   = (const float*)d_in[1];
    const float* V   = (const float*)d_in[2];
    const int*   seg = (const int*)d_in[3];
    float* out = (float*)d_out;

    dim3 pgrid(16, NKV, B_);
    prep_kernel<<<pgrid, 256, 0, stream>>>(K, V);

    dim3 grid(NTILE, NQ, B_);
    fa_kernel<<<grid, 256, 0, stream>>>(Q, seg, out);
}